// Round 1
// baseline (94.609 us; speedup 1.0000x reference)
//
#include <hip/hip_runtime.h>
#include <hip/hip_bf16.h>
#include <math.h>

typedef __attribute__((ext_vector_type(8))) short  short8;
typedef __attribute__((ext_vector_type(4))) float  float4v;

#define NE 64
#define FLAG_CAP 8192
#define EPS_TIE 2e-4f
#define KSPLIT 4
#define TOKB 128

#define BARRIER  asm volatile("s_barrier" ::: "memory")
#define WAITV(n) asm volatile("s_waitcnt vmcnt(" #n ")" ::: "memory")

__device__ __forceinline__ unsigned short f2bf(float x){
  unsigned u = __float_as_uint(x);
  return (unsigned short)((u + 0x7fffu + ((u>>16)&1u)) >> 16);
}
__device__ __forceinline__ float bf2f(unsigned short h){
  return __uint_as_float(((unsigned)h)<<16);
}
__device__ __forceinline__ float warp_sum64(float v){
  #pragma unroll
  for (int off=1; off<64; off<<=1) v += __shfl_xor(v, off, 64);
  return v;
}

// async global->LDS, 16B per lane: dest = lds_base(uniform) + lane*16
__device__ __forceinline__ void gld16(void* lds, const void* g){
  __builtin_amdgcn_global_load_lds(
      (const __attribute__((address_space(1))) unsigned int*)g,
      (__attribute__((address_space(3))) unsigned int*)lds,
      16, 0, 0);
}

// ---------- kernel 1: split W into bf16 hi/lo in MFMA B-frag order (+zero stats) ----------
// frag layout: [ks][te][lane][8]; lane l -> e = te*16 + (l&15), k = ks*32 + (l>>4)*8 + j
__global__ __launch_bounds__(256) void prep_w(
    const float* __restrict__ W, unsigned short* __restrict__ whi,
    unsigned short* __restrict__ wlo, float* __restrict__ zbuf, int K)
{
  if (blockIdx.x == 0){                       // zero imp8[512]+cnt8[512]+flagCnt
    #pragma unroll
    for (int i=0;i<5;++i){
      const int idx = threadIdx.x + i*256;
      if (idx < 1025) zbuf[idx] = 0.f;
    }
  }
  const int id = blockIdx.x*256 + threadIdx.x;
  const int nfrag = (K/32)*4*64;
  if (id >= nfrag) return;
  const int lane = id & 63, te = (id>>6)&3, ks = id>>8;
  const int e  = te*16 + (lane&15);
  const int k0 = ks*32 + ((lane>>4)<<3);
  const float* src = W + (size_t)e*K + k0;
  short8 h8, l8;
  #pragma unroll
  for (int j=0;j<8;++j){
    float x = src[j];
    unsigned short hb = f2bf(x);
    h8[j] = (short)hb;
    l8[j] = (short)f2bf(x - bf2f(hb));
  }
  const size_t off = (size_t)id*8;
  *(short8*)(whi + off) = h8;
  *(short8*)(wlo + off) = l8;
}

// ---------- bf16 hi/lo conversion via packed cvt ----------
__device__ __forceinline__ void cvt8b(const float4& c, const float4& d,
                                      short8& hi, short8& lo){
  const float f[8] = {c.x,c.y,c.z,c.w,d.x,d.y,d.z,d.w};
  union { short8 s; unsigned u[4]; } H, L;
  #pragma unroll
  for (int p=0;p<4;++p){
    float2 v = make_float2(f[2*p], f[2*p+1]);
    __hip_bfloat162 hb = __float22bfloat162_rn(v);
    H.u[p] = *reinterpret_cast<unsigned*>(&hb);
    float2 back = __bfloat1622float2(hb);
    float2 res = make_float2(v.x - back.x, v.y - back.y);
    __hip_bfloat162 lb = __float22bfloat162_rn(res);
    L.u[p] = *reinterpret_cast<unsigned*>(&lb);
  }
  hi = H.s; lo = L.s;
}

#define MFMA3(AH, AL, BH, BL, ACC)                                          \
  ACC = __builtin_amdgcn_mfma_f32_16x16x32_bf16(AH, BH, ACC, 0,0,0);        \
  ACC = __builtin_amdgcn_mfma_f32_16x16x32_bf16(AH, BL, ACC, 0,0,0);        \
  ACC = __builtin_amdgcn_mfma_f32_16x16x32_bf16(AL, BH, ACC, 0,0,0);

// ---------- kernel 2: 128-token blocks; wave = 64tok x 32E quadrant ----------
// B fragments read ONCE per tile into regs, reused across 4 A row-groups:
// per-tile LDS reads drop 640->384 B/token, writes 256->192 B/token.
__global__ __launch_bounds__(256) void gemm_cnt(
    const float* __restrict__ hp, const unsigned short* __restrict__ whi,
    const unsigned short* __restrict__ wlo, float* __restrict__ part,
    int K, long M, int tiles)
{
  __shared__ float          As[2][TOKB*32];  // 2 x 16 KB
  __shared__ unsigned short Bs[2][8*512];    // 2 x 8 KB

  const int tid = threadIdx.x;
  const int l = tid & 63, w = tid >> 6;
  const int tok0  = blockIdx.x * TOKB;
  const int slice = blockIdx.y;
  const int kbase = slice * (tiles*32);
  const int r16 = l & 15, kg = l >> 4;
  const int th = w >> 1;            // token half: rows th*64 .. th*64+63
  const int eh = w & 1;             // expert half: te in {eh*2, eh*2+1}

  float4v acc[4][2];
  #pragma unroll
  for (int m=0;m<4;++m)
    #pragma unroll
    for (int lt=0;lt<2;++lt) acc[m][lt] = (float4v){0.f,0.f,0.f,0.f};

  const unsigned short* bsel[2] = { whi, wlo };
  const int srcblkA = (l&7) ^ (l>>3);        // pre-swizzled source 16B-block

  auto STAGE = [&](int buf, int t){
    #pragma unroll
    for (int i=0;i<4;++i){                   // A: wave w stages rows w*32..+31
      const int row = w*32 + i*8 + (l>>3);   // row%8 == l>>3 (swizzle key)
      const float* src = hp + (size_t)(tok0 + row)*K + kbase + t*32 + (srcblkA<<2);
      gld16((void*)(As[buf] + w*1024 + i*256), (const void*)src);
    }
    #pragma unroll
    for (int i=0;i<2;++i){                   // B: unit u = w*2+i -> (te,d)
      const int u = w*2 + i;
      const int te = u >> 1, d = u & 1;
      const unsigned short* src = bsel[d]
          + ((size_t)(slice*tiles + t))*2048 + te*512 + (size_t)l*8;
      gld16((void*)(Bs[buf] + u*512), (const void*)src);
    }
  };

  auto COMPUTE = [&](int buf){
    short8 Bh[2], Bl[2];                     // B once per tile -> regs (16 VGPRs)
    #pragma unroll
    for (int lt=0; lt<2; ++lt){
      const int te = eh*2 + lt;
      Bh[lt] = *(const short8*)(Bs[buf] + (te*2+0)*512 + l*8);
      Bl[lt] = *(const short8*)(Bs[buf] + (te*2+1)*512 + l*8);
    }
    const int c0 = kg*2, sw = r16 & 7;
    #pragma unroll
    for (int m=0;m<4;++m){
      const float* arow = As[buf] + (th*64 + m*16 + r16)*32;
      float4 a0 = *(const float4*)(arow + (((c0  ) ^ sw) << 2));
      float4 a1 = *(const float4*)(arow + (((c0+1) ^ sw) << 2));
      short8 Ah, Al;
      cvt8b(a0, a1, Ah, Al);
      #pragma unroll
      for (int lt=0; lt<2; ++lt){
        MFMA3(Ah, Al, Bh[lt], Bl[lt], acc[m][lt]);
      }
    }
  };

  STAGE(0, 0);
  STAGE(1, 1);
  WAITV(6); BARRIER;                 // tile0 landed everywhere; tile1 flying
  int t = 0;
  for (; t < tiles-2; ++t){
    COMPUTE(t&1);
    BARRIER;                         // all waves done reading buf cur
    STAGE(t&1, t+2);                 // 12 outstanding/wave
    WAITV(6); BARRIER;               // tile t+1 landed; t+2 still flying
  }
  COMPUTE(t&1);                      // t == tiles-2
  WAITV(0); BARRIER;                 // final drain (once)
  COMPUTE((t+1)&1);

  // C layout (m89-verified): col = lane&15, row = (lane>>4)*4 + reg
  float* dst = part + (size_t)slice*M*NE;
  #pragma unroll
  for (int m=0;m<4;++m)
    #pragma unroll
    for (int lt=0;lt<2;++lt)
      #pragma unroll
      for (int r=0;r<4;++r){
        const int tok = tok0 + th*64 + m*16 + (kg<<2) + r;
        dst[(size_t)tok*NE + (eh*2+lt)*16 + r16] = acc[m][lt][r];
      }
}

// ---------- kernel 3: high-occupancy finish: 16 tokens/block, 4/wave ----------
__global__ __launch_bounds__(256) void router_finish2(
    const float* __restrict__ part, const float* __restrict__ bp,
    float* __restrict__ outp, float* __restrict__ imp8,
    float* __restrict__ cnt8, int* __restrict__ flagCnt,
    int* __restrict__ flagList, long M)
{
  __shared__ float red[2][4][64];
  const int tid = threadIdx.x;
  const int w = tid >> 6, lane = tid & 63;
  const long base = (long)blockIdx.x*16 + w*4;
  const float bias = bp[lane];
  float impL = 0.f, cntL = 0.f;

  #pragma unroll 1
  for (int it=0; it<4; ++it){
    const long t = base + it;
    // deterministic fixed-order partial sum
    float v = part[t*NE + lane];
    v += part[(size_t)M*NE   + t*NE + lane];
    v += part[(size_t)M*NE*2 + t*NE + lane];
    v += part[(size_t)M*NE*3 + t*NE + lane];
    v += bias;
    float m1 = v; int i1 = lane;
    #pragma unroll
    for (int off=1; off<64; off<<=1){
      float ov = __shfl_xor(m1, off, 64);
      int   oi = __shfl_xor(i1, off, 64);
      if (ov > m1 || (ov == m1 && oi < i1)){ m1 = ov; i1 = oi; }
    }
    float vm = (lane == i1) ? -3.4e38f : v;
    float m2 = vm; int i2 = lane;
    #pragma unroll
    for (int off=1; off<64; off<<=1){
      float ov = __shfl_xor(m2, off, 64);
      int   oi = __shfl_xor(i2, off, 64);
      if (ov > m2 || (ov == m2 && oi < i2)){ m2 = ov; i2 = oi; }
    }
    float vm3 = (lane==i1 || lane==i2) ? -3.4e38f : v;
    float m3 = vm3;
    #pragma unroll
    for (int off=1; off<64; off<<=1) m3 = fmaxf(m3, __shfl_xor(m3, off, 64));
    if ((m2 - m3) < EPS_TIE && lane == 0){
      int idx = atomicAdd(flagCnt, 1);
      if (idx < FLAG_CAP) flagList[idx] = (int)t;
    }
    const float ex = __expf(m2 - m1);
    const float s1 = 1.f / (1.f + ex);
    const float s2 = ex * s1;
    const float p = __expf(v - m1);
    const float S = warp_sum64(p);
    impL += p / S;
    const float rw = (lane==i1) ? s1 : ((lane==i2) ? s2 : 0.f);
    outp[t*NE + lane] = rw;
    if (lane==i1 || lane==i2) cntL += 1.f;
  }
  red[0][w][lane] = impL;
  red[1][w][lane] = cntL;
  __syncthreads();
  if (tid < 64){
    float s = red[0][0][tid] + red[0][1][tid] + red[0][2][tid] + red[0][3][tid];
    float c = red[1][0][tid] + red[1][1][tid] + red[1][2][tid] + red[1][3][tid];
    const int g = (blockIdx.x & 7) << 6;   // 8 banks kill atomic serialization
    atomicAdd(&imp8[g + tid], s);
    atomicAdd(&cnt8[g + tid], c);
  }
}

// ---------- kernel 4: fixup (one token per block) + aux fold (block 0) ----------
__global__ __launch_bounds__(256) void fixup_aux(
    const float* __restrict__ hp, const float* __restrict__ Wp,
    const float* __restrict__ bp, float* __restrict__ outp,
    const int* __restrict__ flagCnt, const int* __restrict__ flagList,
    const float* __restrict__ imp8, const float* __restrict__ cnt8,
    float* __restrict__ auxp, float scale, int K)
{
  __shared__ float hrow[4096];
  __shared__ float lg[NE];
  if (blockIdx.x == 0 && threadIdx.x < 64){     // aux: imp/cnt ready (prev kernel)
    float s = 0.f, c = 0.f;
    #pragma unroll
    for (int g=0; g<8; ++g){
      s += imp8[(g<<6) + threadIdx.x];
      c += cnt8[(g<<6) + threadIdx.x];
    }
    float v = s * c;
    v = warp_sum64(v);
    if (threadIdx.x == 0) auxp[0] = v * scale;
  }
  int n = *flagCnt; if (n > FLAG_CAP) n = FLAG_CAP;
  const int e   = threadIdx.x >> 2;
  const int sub = threadIdx.x & 3;
  const int lane = threadIdx.x & 63;

  for (int f = blockIdx.x; f < n; f += gridDim.x){
    const int tok = flagList[f];
    const float* hr = hp + (size_t)tok*K;
    #pragma unroll
    for (int c=0; c<4; ++c){
      const int idx = threadIdx.x*4 + c*1024;
      *(float4*)&hrow[idx] = *(const float4*)(hr + idx);
    }
    __syncthreads();
    const float* wr = Wp + (size_t)e*K;
    float s = 0.f;
    for (int it=0; it<64; ++it){
      const int k0 = it*64 + sub*16;
      #pragma unroll
      for (int u=0; u<4; ++u){
        float4 wv = *(const float4*)(wr + k0 + u*4);
        float4 hv = *(const float4*)(&hrow[k0 + u*4]);
        s = fmaf(hv.x, wv.x, s); s = fmaf(hv.y, wv.y, s);
        s = fmaf(hv.z, wv.z, s); s = fmaf(hv.w, wv.w, s);
      }
    }
    s += __shfl_xor(s, 1, 64);
    s += __shfl_xor(s, 2, 64);
    if (sub == 0) lg[e] = s + bp[e];
    __syncthreads();
    if (threadIdx.x < 64){
      const float v = lg[lane];
      float m1 = v; int i1 = lane;
      #pragma unroll
      for (int off=1; off<64; off<<=1){
        float ov = __shfl_xor(m1, off, 64);
        int   oi = __shfl_xor(i1, off, 64);
        if (ov > m1 || (ov == m1 && oi < i1)){ m1 = ov; i1 = oi; }
      }
      float vm = (lane == i1) ? -3.4e38f : v;
      float m2 = vm; int i2 = lane;
      #pragma unroll
      for (int off=1; off<64; off<<=1){
        float ov = __shfl_xor(m2, off, 64);
        int   oi = __shfl_xor(i2, off, 64);
        if (ov > m2 || (ov == m2 && oi < i2)){ m2 = ov; i2 = oi; }
      }
      const float ex = __expf(m2 - m1);
      const float s1 = 1.f / (1.f + ex);
      const float s2 = ex * s1;
      const float rw = (lane==i1) ? s1 : ((lane==i2) ? s2 : 0.f);
      outp[(size_t)tok * NE + lane] = rw;
    }
    __syncthreads();
  }
}

extern "C" void kernel_launch(void* const* d_in, const int* in_sizes, int n_in,
                              void* d_out, int out_size, void* d_ws, size_t ws_size,
                              hipStream_t stream){
  const float* hp = (const float*)d_in[0];
  const float* Wp = (const float*)d_in[1];
  const float* bp = (const float*)d_in[2];
  const int  E = in_sizes[2];               // 64
  const int  K = in_sizes[1] / E;           // 4096
  const long M = (long)in_sizes[0] / K;     // 16384

  float* outp = (float*)d_out;
  float* auxp = outp + (size_t)M * E;

  char* ws = (char*)d_ws;
  float* imp8     = (float*)(ws + 0);        // 8 x 64 f
  float* cnt8     = (float*)(ws + 2048);     // 8 x 64 f
  int*   flagCnt  = (int*)  (ws + 4096);
  int*   flagList = (int*)  (ws + 4160);     // FLAG_CAP ints
  unsigned short* whi = (unsigned short*)(ws + 65536);            // 512 KB
  unsigned short* wlo = (unsigned short*)(ws + 65536 + 524288);   // 512 KB
  float* part     = (float*)(ws + 1114112); // KSPLIT * M * 64 f = 16 MB

  const int nfragBlocks = ((K/32)*4*64 + 255)/256;
  const int tiles = (K / KSPLIT) / 32;      // 32 tiles of BK=32

  prep_w<<<dim3(nfragBlocks), dim3(256), 0, stream>>>(Wp, whi, wlo, (float*)ws, K);
  gemm_cnt<<<dim3((int)(M/TOKB), KSPLIT), dim3(256), 0, stream>>>(hp, whi, wlo, part, K, M, tiles);
  router_finish2<<<dim3((int)(M/16)), dim3(256), 0, stream>>>(part, bp, outp, imp8, cnt8,
                                                              flagCnt, flagList, M);
  fixup_aux<<<dim3(128), dim3(256), 0, stream>>>(hp, Wp, bp, outp, flagCnt, flagList,
                                                 imp8, cnt8, auxp, (float)E/(float)M, K);
}